// Round 8
// baseline (1889.393 us; speedup 1.0000x reference)
//
#include <hip/hip_runtime.h>
#include <math.h>

// B=64, S=64, H_DIM=768, N_HEADS=12, D=64. All I/O f32.
// ONE fused kernel, grid=1024 blocks x 256 thr, 4 blocks/CU co-resident
// (forced via __launch_bounds__(256,4) + 36KB LDS) -> manual grid barriers
// with device-scope atomics are safe. 3 barriers between 4 phases.
// ws bytes: qkvb u16[9437184] @0 ; Zh u16[3145728] @18874368 ;
//           part f32[8388608] @25165824 ; ctr u32[3] @58720256 (memset per launch)
// d_out f32: y [262144] then masked_scores [3145728].
// Masked positions: ref=-inf -> finite NEG_BIG (never materialize inf:
// finite-math folds ==-INFINITY; expf(NEG_BIG-m)==0).
// All GEMMs plain bf16 MFMA (f32 accum), ~0.5% rel err, within tolerance.
// mfma_f32_16x16x32_bf16: A row=ln&15,k=(ln>>4)*8+j; B col=ln&15; C/D col=ln&15,row=(ln>>4)*4+reg.
// Z frag order: z_flat[b][k] at ((rt*1536+kf)*64+lz)*8+j, rt=b>>4, kf=k>>5,
// lz=((k>>3)&3)*16+(b&15), j=k&7 -> lin's A-fragment = one contiguous 1KB wave read.

#define NEG_BIG (-1.0e30f)
#define NBLK 1024

typedef __attribute__((ext_vector_type(8))) short bf16x8;
typedef __attribute__((ext_vector_type(4))) float f32x4;
typedef const __attribute__((address_space(1))) void gvoid_t;
typedef __attribute__((address_space(3))) void svoid_t;

static __device__ __forceinline__ unsigned short f2bf(float x) {
    unsigned u = __builtin_bit_cast(unsigned, x);
    return (unsigned short)((u + 0x7FFFu + ((u >> 16) & 1u)) >> 16);   // RNE
}
static __device__ __forceinline__ ushort4 f2bf4(float4 v) {
    ushort4 r; r.x = f2bf(v.x); r.y = f2bf(v.y); r.z = f2bf(v.z); r.w = f2bf(v.w); return r;
}
static __device__ __forceinline__ bf16x8 cvt8(float4 a, float4 b) {
    bf16x8 h;
    h[0] = (short)f2bf(a.x); h[1] = (short)f2bf(a.y); h[2] = (short)f2bf(a.z); h[3] = (short)f2bf(a.w);
    h[4] = (short)f2bf(b.x); h[5] = (short)f2bf(b.y); h[6] = (short)f2bf(b.z); h[7] = (short)f2bf(b.w);
    return h;
}

static __device__ __forceinline__ void grid_barrier(unsigned* c) {
    __syncthreads();
    __threadfence();                                   // release: prior writes visible device-wide
    if (threadIdx.x == 0) {
        __hip_atomic_fetch_add(c, 1u, __ATOMIC_ACQ_REL, __HIP_MEMORY_SCOPE_AGENT);
        while (__hip_atomic_load(c, __ATOMIC_ACQUIRE, __HIP_MEMORY_SCOPE_AGENT) < NBLK)
            __builtin_amdgcn_s_sleep(2);
    }
    __syncthreads();
    __threadfence();                                   // acquire side
}

__global__ __launch_bounds__(256, 4) void fused(const float* __restrict__ X,
                                                const float* __restrict__ Wp,
                                                const float* __restrict__ Wl,
                                                const float* __restrict__ bl,
                                                float* __restrict__ out,
                                                unsigned short* __restrict__ qkvb,
                                                unsigned short* __restrict__ Zh,
                                                float* __restrict__ part,
                                                unsigned* __restrict__ ctr) {
    __shared__ __align__(16) unsigned char lds_raw[36864];
    const int t   = threadIdx.x;
    const int bid = blockIdx.x;
    const int wv  = t >> 6, ln = t & 63;
    const int lr  = ln & 15;
    const int kq  = (ln >> 4) * 8;
    const int rbase = (ln >> 4) * 4;
    const f32x4 zero4 = {0.f, 0.f, 0.f, 0.f};

    // ================= Phase 1: QKV GEMM (blocks 0..575) =================
    if (bid < 576) {
        unsigned short (*Ah)[72] = reinterpret_cast<unsigned short(*)[72]>(lds_raw);
        unsigned short (*Bh)[72] = reinterpret_cast<unsigned short(*)[72]>(lds_raw + 18432);
        const int m0 = (bid / 18) * 128;
        const int j0 = (bid % 18) * 128;

        f32x4 acc[2][8];
#pragma unroll
        for (int rt = 0; rt < 2; ++rt)
#pragma unroll
            for (int ct = 0; ct < 8; ++ct) acc[rt][ct] = zero4;

        for (int k0 = 0; k0 < 768; k0 += 64) {
#pragma unroll
            for (int i = 0; i < 8; ++i) {
                const int q   = t + 256 * i;
                const int row = q >> 4;
                const int kc  = (q & 15) * 4;
                float4 xa = *reinterpret_cast<const float4*>(&X[(size_t)(m0 + row) * 768 + k0 + kc]);
                *reinterpret_cast<ushort4*>(&Ah[row][kc]) = f2bf4(xa);
                float4 wb = *reinterpret_cast<const float4*>(&Wp[(size_t)(j0 + row) * 768 + k0 + kc]);
                *reinterpret_cast<ushort4*>(&Bh[row][kc]) = f2bf4(wb);
            }
            __syncthreads();
#pragma unroll
            for (int ks = 0; ks < 2; ++ks) {
                const int kb = ks * 32 + kq;
                bf16x8 a0 = *reinterpret_cast<const bf16x8*>(&Ah[wv * 32 + lr][kb]);
                bf16x8 a1 = *reinterpret_cast<const bf16x8*>(&Ah[wv * 32 + 16 + lr][kb]);
#pragma unroll
                for (int ct = 0; ct < 8; ++ct) {
                    bf16x8 bh = *reinterpret_cast<const bf16x8*>(&Bh[ct * 16 + lr][kb]);
                    acc[0][ct] = __builtin_amdgcn_mfma_f32_16x16x32_bf16(a0, bh, acc[0][ct], 0, 0, 0);
                    acc[1][ct] = __builtin_amdgcn_mfma_f32_16x16x32_bf16(a1, bh, acc[1][ct], 0, 0, 0);
                }
            }
            __syncthreads();
        }
#pragma unroll
        for (int rt = 0; rt < 2; ++rt)
#pragma unroll
            for (int ct = 0; ct < 8; ++ct)
#pragma unroll
                for (int r = 0; r < 4; ++r) {
                    const int m = m0 + wv * 32 + rt * 16 + rbase + r;
                    const int j = j0 + ct * 16 + lr;
                    const int b = m >> 6, s = m & 63;
                    const int n = j / 192, f = j % 192;
                    qkvb[(((size_t)b * 12 + n) * 64 + s) * 192 + f] = f2bf(acc[rt][ct][r]);
                }
    }
    grid_barrier(ctr + 0);

    // ================= Phase 2: attention (blocks 0..767) =================
    if (bid < 768) {
        unsigned short (*Qh)[72]  = reinterpret_cast<unsigned short(*)[72]>(lds_raw);
        unsigned short (*Kh)[72]  = reinterpret_cast<unsigned short(*)[72]>(lds_raw + 9216);
        unsigned short (*Vth)[72] = reinterpret_cast<unsigned short(*)[72]>(lds_raw + 18432);
        unsigned short (*Ph)[72]  = reinterpret_cast<unsigned short(*)[72]>(lds_raw + 27648);
        const int bn = bid;
        const int bb = bn / 12, nn = bn % 12;
        const unsigned short* base = qkvb + (size_t)bn * 12288;
        float* msk = out + 262144;

#pragma unroll
        for (int i = 0; i < 6; ++i) {
            const int q   = t + 256 * i;       // 1536 ushort8 granules
            const int row = q / 24;
            const int c8  = (q % 24) * 8;
            const int sec = c8 >> 6;
            const int d0  = c8 & 63;
            bf16x8 v = *reinterpret_cast<const bf16x8*>(&base[(size_t)row * 192 + c8]);
            if (sec == 0) {
                *reinterpret_cast<bf16x8*>(&Qh[row][d0]) = v;
            } else if (sec == 1) {
                *reinterpret_cast<bf16x8*>(&Kh[row][d0]) = v;
            } else {
#pragma unroll
                for (int jj = 0; jj < 8; ++jj) Vth[d0 + jj][row] = (unsigned short)v[jj];
            }
        }
        __syncthreads();

        // S = Q K^T / 8 ; wave owns rows [wv*16, wv*16+16)
        f32x4 acc[4];
#pragma unroll
        for (int ct = 0; ct < 4; ++ct) acc[ct] = zero4;
#pragma unroll
        for (int ks = 0; ks < 2; ++ks) {
            const int kb = ks * 32 + kq;
            bf16x8 qh = *reinterpret_cast<const bf16x8*>(&Qh[wv * 16 + lr][kb]);
#pragma unroll
            for (int ct = 0; ct < 4; ++ct) {
                bf16x8 kh = *reinterpret_cast<const bf16x8*>(&Kh[ct * 16 + lr][kb]);
                acc[ct] = __builtin_amdgcn_mfma_f32_16x16x32_bf16(qh, kh, acc[ct], 0, 0, 0);
            }
        }

        float s_[4][4];
#pragma unroll
        for (int ct = 0; ct < 4; ++ct)
#pragma unroll
            for (int r = 0; r < 4; ++r) {
                const int row = wv * 16 + rbase + r;
                const int col = ct * 16 + lr;
                float s = (col > row) ? NEG_BIG : acc[ct][r] * 0.125f;
                s_[ct][r] = s;
                msk[(size_t)bn * 4096 + (size_t)row * 64 + col] = s;
            }
        float m[4], sum[4], p[4][4];
#pragma unroll
        for (int r = 0; r < 4; ++r)
            m[r] = fmaxf(fmaxf(s_[0][r], s_[1][r]), fmaxf(s_[2][r], s_[3][r]));
#pragma unroll
        for (int off = 1; off <= 8; off <<= 1)
#pragma unroll
            for (int r = 0; r < 4; ++r) m[r] = fmaxf(m[r], __shfl_xor(m[r], off));
#pragma unroll
        for (int r = 0; r < 4; ++r) sum[r] = 0.f;
#pragma unroll
        for (int ct = 0; ct < 4; ++ct)
#pragma unroll
            for (int r = 0; r < 4; ++r) { p[ct][r] = expf(s_[ct][r] - m[r]); sum[r] += p[ct][r]; }
#pragma unroll
        for (int off = 1; off <= 8; off <<= 1)
#pragma unroll
            for (int r = 0; r < 4; ++r) sum[r] += __shfl_xor(sum[r], off);
#pragma unroll
        for (int ct = 0; ct < 4; ++ct)
#pragma unroll
            for (int r = 0; r < 4; ++r)
                Ph[wv * 16 + rbase + r][ct * 16 + lr] = f2bf(p[ct][r] * (1.f / sum[r]));
        // wave-local LDS dependency only (compiler inserts lgkmcnt)

        f32x4 o_[4];
#pragma unroll
        for (int ct = 0; ct < 4; ++ct) o_[ct] = zero4;
#pragma unroll
        for (int ks = 0; ks < 2; ++ks) {
            const int kb = ks * 32 + kq;
            bf16x8 ph = *reinterpret_cast<const bf16x8*>(&Ph[wv * 16 + lr][kb]);
#pragma unroll
            for (int ct = 0; ct < 4; ++ct) {
                bf16x8 vh = *reinterpret_cast<const bf16x8*>(&Vth[ct * 16 + lr][kb]);
                o_[ct] = __builtin_amdgcn_mfma_f32_16x16x32_bf16(ph, vh, o_[ct], 0, 0, 0);
            }
        }
        const int rt_z = bb >> 4;
#pragma unroll
        for (int ct = 0; ct < 4; ++ct)
#pragma unroll
            for (int r = 0; r < 4; ++r) {
                const int srow = wv * 16 + rbase + r;
                const int d    = ct * 16 + lr;
                const int k    = nn * 4096 + srow * 64 + d;
                const int lz   = (((k >> 3) & 3) << 4) + (bb & 15);
                const size_t zi = (((size_t)rt_z * 1536 + (k >> 5)) * 64 + lz) * 8 + (k & 7);
                Zh[zi] = f2bf(o_[ct][r]);
            }
    }
    grid_barrier(ctr + 1);

    // ================= Phase 3: output projection (all blocks, 2 units) =================
    {
        float (*ldsw)[4][16][64] = reinterpret_cast<float(*)[4][16][64]>(lds_raw);
        const int ksp  = bid >> 5;                  // 0..31
        const int kbeg = ksp * 1536;

#define STAGE(buf, kstep)                                                              \
        {                                                                              \
            const int k0f = kbeg + (kstep) * 64;                                       \
            _Pragma("unroll")                                                          \
            for (int i = 0; i < 4; ++i) {                                              \
                const int row_l = i * 4 + (ln >> 4);                                   \
                const int u_g   = (ln & 15) ^ (row_l & 7);                             \
                const float* src = Wl + (size_t)(o0 + wv * 16 + row_l) * 49152 + k0f + u_g * 4; \
                __builtin_amdgcn_global_load_lds((gvoid_t*)src,                        \
                    (svoid_t*)&ldsw[buf][wv][i * 4][0], 16, 0, 0);                     \
            }                                                                          \
        }

        for (int u = 0; u < 2; ++u) {
            const int ob = ((bid & 31) << 1) | u;   // both units share ksp -> Z L2-hot
            const int o0 = ob * 64;

            f32x4 acc[4];
#pragma unroll
            for (int rt = 0; rt < 4; ++rt) acc[rt] = zero4;

            STAGE(0, 0)
            for (int ts = 0; ts < 24; ++ts) {
                if (ts + 1 < 24) {
                    if ((ts + 1) & 1) STAGE(1, ts + 1) else STAGE(0, ts + 1)
                    asm volatile("s_waitcnt vmcnt(4)" ::: "memory");
                } else {
                    asm volatile("s_waitcnt vmcnt(0)" ::: "memory");
                }
                const int buf = ts & 1;
                const int kf0 = ksp * 48 + ts * 2;
#pragma unroll
                for (int ks = 0; ks < 2; ++ks) {
                    const int u0 = ks * 8 + (ln >> 4) * 2;
                    const char* rowp = (const char*)&ldsw[buf][wv][lr][0];
                    float4 f0 = *reinterpret_cast<const float4*>(rowp + ((u0 ^ (lr & 7)) << 4));
                    float4 f1 = *reinterpret_cast<const float4*>(rowp + (((u0 + 1) ^ (lr & 7)) << 4));
                    bf16x8 wh = cvt8(f0, f1);
                    const size_t zoff = ((size_t)(kf0 + ks) * 64 + ln) * 8;
#pragma unroll
                    for (int rt = 0; rt < 4; ++rt) {
                        bf16x8 ah = *reinterpret_cast<const bf16x8*>(Zh + (size_t)rt * 786432 + zoff);
                        acc[rt] = __builtin_amdgcn_mfma_f32_16x16x32_bf16(ah, wh, acc[rt], 0, 0, 0);
                    }
                }
            }
            const int ocol = o0 + wv * 16 + lr;
#pragma unroll
            for (int rt = 0; rt < 4; ++rt)
#pragma unroll
                for (int r = 0; r < 4; ++r)
                    part[((size_t)ksp * 64 + rt * 16 + rbase + r) * 4096 + ocol] = acc[rt][r];
        }
#undef STAGE
    }
    grid_barrier(ctr + 2);

    // ================= Phase 4: reduce split-K + bias =================
    {
        const int idx = bid * 256 + t;              // 0..262143
        const int o = idx & 4095;
        const int b = idx >> 12;
        float s = bl[o];
#pragma unroll
        for (int ksp = 0; ksp < 32; ++ksp)
            s += part[((size_t)ksp * 64 + b) * 4096 + o];
        out[idx] = s;
    }
}

extern "C" void kernel_launch(void* const* d_in, const int* in_sizes, int n_in,
                              void* d_out, int out_size, void* d_ws, size_t ws_size,
                              hipStream_t stream) {
    const float* x  = (const float*)d_in[0];
    const float* Wp = (const float*)d_in[1];
    const float* Wl = (const float*)d_in[2];
    const float* bl = (const float*)d_in[3];
    float* out = (float*)d_out;

    unsigned short* qkvb = (unsigned short*)d_ws;                       // 9437184 u16
    unsigned short* Zh   = (unsigned short*)((char*)d_ws + 18874368);   // 3145728 u16
    float*          part = (float*)((char*)d_ws + 25165824);            // 8388608 f32
    unsigned*       ctr  = (unsigned*)((char*)d_ws + 58720256);         // 3 u32

    hipMemsetAsync(ctr, 0, 3 * sizeof(unsigned), stream);
    hipLaunchKernelGGL(fused, dim3(NBLK), dim3(256), 0, stream,
                       x, Wp, Wl, bl, out, qkvb, Zh, part, ctr);
}

// Round 9
// 344.756 us; speedup vs baseline: 5.4804x; 5.4804x over previous
//
#include <hip/hip_runtime.h>
#include <math.h>

// B=64, S=64, H_DIM=768, N_HEADS=12, D=64. All I/O f32.
// 4 kernels (grid barriers abandoned: device-scope fences = cross-XCD L2
// flush/invalidate storms; kernel boundaries give coherence for free).
// ws bytes: qkvb u16[9437184] @0 ; Zh u16[3145728] @18874368 ;
//           part f32[8388608] @25165824
// d_out f32: y [262144] then masked_scores [3145728].
// Masked positions: ref=-inf -> finite NEG_BIG (never materialize inf:
// finite-math folds ==-INFINITY; expf(NEG_BIG-m)==0).
// All GEMMs plain bf16 MFMA, f32 accum (r8 proved threshold tolerates bf16).
// mfma_f32_16x16x32_bf16: A row=ln&15,k=(ln>>4)*8+j; B col=ln&15;
// C/D col=ln&15,row=(ln>>4)*4+reg.
// Z frag order: z_flat[b][k] at ((rt*1536+kf)*64+lz)*8+j, rt=b>>4, kf=k>>5,
// lz=((k>>3)&3)*16+(b&15), j=k&7 -> k_lin A-fragment = contiguous 1KB wave read.

#define NEG_BIG (-1.0e30f)

typedef __attribute__((ext_vector_type(8))) short bf16x8;
typedef __attribute__((ext_vector_type(4))) float f32x4;
typedef const __attribute__((address_space(1))) void gvoid_t;
typedef __attribute__((address_space(3))) void svoid_t;

static __device__ __forceinline__ unsigned short f2bf(float x) {
    unsigned u = __builtin_bit_cast(unsigned, x);
    return (unsigned short)((u + 0x7FFFu + ((u >> 16) & 1u)) >> 16);   // RNE
}
static __device__ __forceinline__ ushort4 f2bf4(float4 v) {
    ushort4 r; r.x = f2bf(v.x); r.y = f2bf(v.y); r.z = f2bf(v.z); r.w = f2bf(v.w); return r;
}
static __device__ __forceinline__ bf16x8 cvt8(float4 a, float4 b) {
    bf16x8 h;
    h[0] = (short)f2bf(a.x); h[1] = (short)f2bf(a.y); h[2] = (short)f2bf(a.z); h[3] = (short)f2bf(a.w);
    h[4] = (short)f2bf(b.x); h[5] = (short)f2bf(b.y); h[6] = (short)f2bf(b.z); h[7] = (short)f2bf(b.w);
    return h;
}

// ---------------- Kernel 1: QKV GEMM, plain bf16 MFMA ----------------
__global__ __launch_bounds__(256, 4) void k_qkv(const float* __restrict__ X,
                                                const float* __restrict__ Wp,
                                                unsigned short* __restrict__ qkvb) {
    __shared__ unsigned short Ah[128][72];
    __shared__ unsigned short Bh[128][72];
    const int t  = threadIdx.x;
    const int wv = t >> 6, ln = t & 63;
    const int lr = ln & 15;
    const int kq = (ln >> 4) * 8;
    const int rbase = (ln >> 4) * 4;
    const int m0 = (blockIdx.x / 18) * 128;
    const int j0 = (blockIdx.x % 18) * 128;
    const f32x4 zero4 = {0.f, 0.f, 0.f, 0.f};

    f32x4 acc[2][8];
#pragma unroll
    for (int rt = 0; rt < 2; ++rt)
#pragma unroll
        for (int ct = 0; ct < 8; ++ct) acc[rt][ct] = zero4;

    for (int k0 = 0; k0 < 768; k0 += 64) {
#pragma unroll
        for (int i = 0; i < 8; ++i) {
            const int q   = t + 256 * i;
            const int row = q >> 4;
            const int kc  = (q & 15) * 4;
            float4 xa = *reinterpret_cast<const float4*>(&X[(size_t)(m0 + row) * 768 + k0 + kc]);
            *reinterpret_cast<ushort4*>(&Ah[row][kc]) = f2bf4(xa);
            float4 wb = *reinterpret_cast<const float4*>(&Wp[(size_t)(j0 + row) * 768 + k0 + kc]);
            *reinterpret_cast<ushort4*>(&Bh[row][kc]) = f2bf4(wb);
        }
        __syncthreads();
#pragma unroll
        for (int ks = 0; ks < 2; ++ks) {
            const int kb = ks * 32 + kq;
            bf16x8 a0 = *reinterpret_cast<const bf16x8*>(&Ah[wv * 32 + lr][kb]);
            bf16x8 a1 = *reinterpret_cast<const bf16x8*>(&Ah[wv * 32 + 16 + lr][kb]);
#pragma unroll
            for (int ct = 0; ct < 8; ++ct) {
                bf16x8 bh = *reinterpret_cast<const bf16x8*>(&Bh[ct * 16 + lr][kb]);
                acc[0][ct] = __builtin_amdgcn_mfma_f32_16x16x32_bf16(a0, bh, acc[0][ct], 0, 0, 0);
                acc[1][ct] = __builtin_amdgcn_mfma_f32_16x16x32_bf16(a1, bh, acc[1][ct], 0, 0, 0);
            }
        }
        __syncthreads();
    }
#pragma unroll
    for (int rt = 0; rt < 2; ++rt)
#pragma unroll
        for (int ct = 0; ct < 8; ++ct)
#pragma unroll
            for (int r = 0; r < 4; ++r) {
                const int m = m0 + wv * 32 + rt * 16 + rbase + r;
                const int j = j0 + ct * 16 + lr;
                const int b = m >> 6, s = m & 63;
                const int n = j / 192, f = j % 192;
                qkvb[(((size_t)b * 12 + n) * 64 + s) * 192 + f] = f2bf(acc[rt][ct][r]);
            }
}

// ---------------- Kernel 2: attention per (b,n), plain bf16 MFMA ----------------
__global__ __launch_bounds__(256, 4) void k_attn(const unsigned short* __restrict__ qkvb,
                                                 float* __restrict__ msk,
                                                 unsigned short* __restrict__ Zh) {
    __shared__ unsigned short Qh[64][72];
    __shared__ unsigned short Kh[64][72];
    __shared__ unsigned short Vth[64][72];   // V transposed [d][s]
    __shared__ unsigned short Ph[64][72];
    const int t  = threadIdx.x;
    const int wv = t >> 6, ln = t & 63;
    const int lr = ln & 15;
    const int kq = (ln >> 4) * 8;
    const int rbase = (ln >> 4) * 4;
    const int bn = blockIdx.x;
    const int bb = bn / 12, nn = bn % 12;
    const unsigned short* base = qkvb + (size_t)bn * 12288;
    const f32x4 zero4 = {0.f, 0.f, 0.f, 0.f};

#pragma unroll
    for (int i = 0; i < 6; ++i) {
        const int q   = t + 256 * i;       // 1536 ushort8 granules
        const int row = q / 24;
        const int c8  = (q % 24) * 8;
        const int sec = c8 >> 6;
        const int d0  = c8 & 63;
        bf16x8 v = *reinterpret_cast<const bf16x8*>(&base[(size_t)row * 192 + c8]);
        if (sec == 0) {
            *reinterpret_cast<bf16x8*>(&Qh[row][d0]) = v;
        } else if (sec == 1) {
            *reinterpret_cast<bf16x8*>(&Kh[row][d0]) = v;
        } else {
#pragma unroll
            for (int jj = 0; jj < 8; ++jj) Vth[d0 + jj][row] = (unsigned short)v[jj];
        }
    }
    __syncthreads();

    f32x4 acc[4];
#pragma unroll
    for (int ct = 0; ct < 4; ++ct) acc[ct] = zero4;
#pragma unroll
    for (int ks = 0; ks < 2; ++ks) {
        const int kb = ks * 32 + kq;
        bf16x8 qh = *reinterpret_cast<const bf16x8*>(&Qh[wv * 16 + lr][kb]);
#pragma unroll
        for (int ct = 0; ct < 4; ++ct) {
            bf16x8 kh = *reinterpret_cast<const bf16x8*>(&Kh[ct * 16 + lr][kb]);
            acc[ct] = __builtin_amdgcn_mfma_f32_16x16x32_bf16(qh, kh, acc[ct], 0, 0, 0);
        }
    }

    float s_[4][4];
#pragma unroll
    for (int ct = 0; ct < 4; ++ct)
#pragma unroll
        for (int r = 0; r < 4; ++r) {
            const int row = wv * 16 + rbase + r;
            const int col = ct * 16 + lr;
            float s = (col > row) ? NEG_BIG : acc[ct][r] * 0.125f;
            s_[ct][r] = s;
            msk[(size_t)bn * 4096 + (size_t)row * 64 + col] = s;
        }
    float m[4], sum[4], p[4][4];
#pragma unroll
    for (int r = 0; r < 4; ++r)
        m[r] = fmaxf(fmaxf(s_[0][r], s_[1][r]), fmaxf(s_[2][r], s_[3][r]));
#pragma unroll
    for (int off = 1; off <= 8; off <<= 1)
#pragma unroll
        for (int r = 0; r < 4; ++r) m[r] = fmaxf(m[r], __shfl_xor(m[r], off));
#pragma unroll
    for (int r = 0; r < 4; ++r) sum[r] = 0.f;
#pragma unroll
    for (int ct = 0; ct < 4; ++ct)
#pragma unroll
        for (int r = 0; r < 4; ++r) { p[ct][r] = expf(s_[ct][r] - m[r]); sum[r] += p[ct][r]; }
#pragma unroll
    for (int off = 1; off <= 8; off <<= 1)
#pragma unroll
        for (int r = 0; r < 4; ++r) sum[r] += __shfl_xor(sum[r], off);
#pragma unroll
    for (int ct = 0; ct < 4; ++ct)
#pragma unroll
        for (int r = 0; r < 4; ++r)
            Ph[wv * 16 + rbase + r][ct * 16 + lr] = f2bf(p[ct][r] * (1.f / sum[r]));
    // wave-local LDS dependency only

    f32x4 o_[4];
#pragma unroll
    for (int ct = 0; ct < 4; ++ct) o_[ct] = zero4;
#pragma unroll
    for (int ks = 0; ks < 2; ++ks) {
        const int kb = ks * 32 + kq;
        bf16x8 ph = *reinterpret_cast<const bf16x8*>(&Ph[wv * 16 + lr][kb]);
#pragma unroll
        for (int ct = 0; ct < 4; ++ct) {
            bf16x8 vh = *reinterpret_cast<const bf16x8*>(&Vth[ct * 16 + lr][kb]);
            o_[ct] = __builtin_amdgcn_mfma_f32_16x16x32_bf16(ph, vh, o_[ct], 0, 0, 0);
        }
    }
    const int rt_z = bb >> 4;
#pragma unroll
    for (int ct = 0; ct < 4; ++ct)
#pragma unroll
        for (int r = 0; r < 4; ++r) {
            const int srow = wv * 16 + rbase + r;
            const int d    = ct * 16 + lr;
            const int k    = nn * 4096 + srow * 64 + d;
            const int lz   = (((k >> 3) & 3) << 4) + (bb & 15);
            const size_t zi = (((size_t)rt_z * 1536 + (k >> 5)) * 64 + lz) * 8 + (k & 7);
            Zh[zi] = f2bf(o_[ct][r]);
        }
}

// ---------------- Kernel 3: output projection, depth-2 pipelined staging ----------------
// part[ksp][b][o] = sum_k Z[b][k] W[o][k]; KSPLIT=32 (chunk 1536), BK=64,
// 3 LDS buffers, wave-private staging (no barriers). Issue order per iter:
// Z(ts+1) reg-loads -> STAGE(ts+2) -> vmcnt(16): in-order vmcnt completion
// forces Z(ts)+S(ts) while leaving S(ts+1),S(ts+2),Z(ts+1) in flight
// -> each W stage lives 2 compute periods (true depth-2).
__global__ __launch_bounds__(256, 3) void k_lin(const unsigned short* __restrict__ Zh,
                                                const float* __restrict__ Wl,
                                                float* __restrict__ part) {
    __shared__ float ldsw[3][4][16][64];   // 48KB -> 3 blocks/CU
    const int t  = threadIdx.x;
    const int wv = t >> 6, ln = t & 63;
    const int lr = ln & 15;
    const int rbase = (ln >> 4) * 4;
    const int ksp  = blockIdx.x >> 5;
    const int kbeg = ksp * 1536;
    const f32x4 zero4 = {0.f, 0.f, 0.f, 0.f};

#define ZLOAD(dst, ts_)                                                            \
    {                                                                              \
        const int tcl = ((ts_) <= 23) ? (ts_) : 23;                                \
        const int kf0 = ksp * 48 + tcl * 2;                                        \
        _Pragma("unroll")                                                          \
        for (int q = 0; q < 8; ++q) {                                              \
            const int ks_ = q & 1, rt_ = q >> 1;                                   \
            dst[q] = *reinterpret_cast<const bf16x8*>(                             \
                Zh + (size_t)rt_ * 786432 + ((size_t)(kf0 + ks_) * 64 + ln) * 8);  \
        }                                                                          \
    }

#define STAGE(bufm, kstep)                                                         \
    {                                                                              \
        const int kcl = ((kstep) <= 23) ? (kstep) : 23;                            \
        const int k0f = kbeg + kcl * 64;                                           \
        _Pragma("unroll")                                                          \
        for (int i = 0; i < 4; ++i) {                                              \
            const int row_l = i * 4 + (ln >> 4);                                   \
            const int u_g   = (ln & 15) ^ (row_l & 7);                             \
            const float* src = Wl + (size_t)(o0 + wv * 16 + row_l) * 49152 + k0f + u_g * 4; \
            __builtin_amdgcn_global_load_lds((gvoid_t*)src,                        \
                (svoid_t*)&ldsw[bufm][wv][i * 4][0], 16, 0, 0);                    \
        }                                                                          \
    }

#define BODY(ts_, zc, zn)                                                          \
    {                                                                              \
        ZLOAD(zn, (ts_) + 1)                                                       \
        STAGE(((ts_) + 2) % 3, (ts_) + 2)                                          \
        asm volatile("s_waitcnt vmcnt(16)" ::: "memory");                          \
        __builtin_amdgcn_sched_barrier(0);                                         \
        const int bufc = (ts_) % 3;                                                \
        _Pragma("unroll")                                                          \
        for (int ks_ = 0; ks_ < 2; ++ks_) {                                        \
            const int u0 = ks_ * 8 + (ln >> 4) * 2;                                \
            const char* rowp = (const char*)&ldsw[bufc][wv][lr][0];                \
            float4 f0 = *reinterpret_cast<const float4*>(rowp + ((u0 ^ (lr & 7)) << 4));       \
            float4 f1 = *reinterpret_cast<const float4*>(rowp + (((u0 + 1) ^ (lr & 7)) << 4)); \
            bf16x8 wh = cvt8(f0, f1);                                              \
            _Pragma("unroll")                                                      \
            for (int rt_ = 0; rt_ < 4; ++rt_)                                      \
                acc[rt_] = __builtin_amdgcn_mfma_f32_16x16x32_bf16(                \
                    zc[rt_ * 2 + ks_], wh, acc[rt_], 0, 0, 0);                     \
        }                                                                          \
    }

    for (int u = 0; u < 2; ++u) {
        const int ob = ((blockIdx.x & 31) << 1) | u;   // units share ksp -> Z L1/L2-hot
        const int o0 = ob * 64;

        f32x4 acc[4];
#pragma unroll
        for (int rt = 0; rt < 4; ++rt) acc[rt] = zero4;

        bf16x8 zA[8], zB[8];
        STAGE(0, 0)          // oldest
        ZLOAD(zA, 0)
        STAGE(1, 1)          // newer than Z(0): waiting for Z(0) leaves it in flight
        for (int ts = 0; ts < 24; ts += 2) {
            BODY(ts,     zA, zB)
            BODY(ts + 1, zB, zA)
        }
        asm volatile("s_waitcnt vmcnt(0)" ::: "memory");   // drain before next unit reuses bufs

        const int ocol = o0 + wv * 16 + lr;
#pragma unroll
        for (int rt = 0; rt < 4; ++rt)
#pragma unroll
            for (int r = 0; r < 4; ++r)
                part[((size_t)ksp * 64 + rt * 16 + rbase + r) * 4096 + ocol] = acc[rt][r];
    }
#undef ZLOAD
#undef STAGE
#undef BODY
}

// ---------------- Kernel 4: reduce 32 split-K partials + bias ----------------
__global__ __launch_bounds__(256) void k_reduce(const float* __restrict__ part,
                                                const float* __restrict__ bias,
                                                float* __restrict__ y) {
    const int idx = blockIdx.x * 256 + threadIdx.x;
    const int o = idx & 4095;
    const int b = idx >> 12;
    float s = bias[o];
#pragma unroll
    for (int ksp = 0; ksp < 32; ++ksp)
        s += part[((size_t)ksp * 64 + b) * 4096 + o];
    y[idx] = s;
}

extern "C" void kernel_launch(void* const* d_in, const int* in_sizes, int n_in,
                              void* d_out, int out_size, void* d_ws, size_t ws_size,
                              hipStream_t stream) {
    const float* x  = (const float*)d_in[0];
    const float* Wp = (const float*)d_in[1];
    const float* Wl = (const float*)d_in[2];
    const float* bl = (const float*)d_in[3];
    float* out = (float*)d_out;

    unsigned short* qkvb = (unsigned short*)d_ws;                       // 9437184 u16
    unsigned short* Zh   = (unsigned short*)((char*)d_ws + 18874368);   // 3145728 u16
    float*          part = (float*)((char*)d_ws + 25165824);            // 8388608 f32
    float* y    = out;
    float* msk  = out + 262144;

    hipLaunchKernelGGL(k_qkv,    dim3(576),  dim3(256), 0, stream, x, Wp, qkvb);
    hipLaunchKernelGGL(k_attn,   dim3(768),  dim3(256), 0, stream, qkvb, msk, Zh);
    hipLaunchKernelGGL(k_lin,    dim3(1024), dim3(256), 0, stream, Zh, Wl, part);
    hipLaunchKernelGGL(k_reduce, dim3(1024), dim3(256), 0, stream, part, bl, y);
}

// Round 10
// 316.595 us; speedup vs baseline: 5.9679x; 1.0890x over previous
//
#include <hip/hip_runtime.h>
#include <math.h>

// B=64, S=64, H_DIM=768, N_HEADS=12, D=64. All I/O f32.
// 4 kernels. ws bytes: qkvb u16[9437184] @0 ; Zh u16[3145728] @18874368 ;
//           part f32[16][64][4096] @25165824
// d_out f32: y [262144] then masked_scores [3145728].
// Masked positions: ref=-inf -> finite NEG_BIG (never materialize inf:
// finite-math folds ==-INFINITY; expf(NEG_BIG-m)==0).
// All GEMMs plain bf16 MFMA, f32 accum (threshold tolerates bf16).
// mfma_f32_16x16x32_bf16: A row=ln&15,k=(ln>>4)*8+j; B col=ln&15;
// C/D col=ln&15,row=(ln>>4)*4+reg.
// Z frag order: z_flat[b][k] at ((rt*1536+kf)*64+lz)*8+j, rt=b>>4, kf=k>>5,
// lz=((k>>3)&3)*16+(b&15), j=k&7 -> contiguous 1KB wave reads / stages.
// k_lin v5: Z staged in LDS once per block per K-step (shared by 4 waves x
// 2 units) -> Z L2/L3 traffic 1.5GB -> 192MB; W stays wave-private swizzled.

#define NEG_BIG (-1.0e30f)

typedef __attribute__((ext_vector_type(8))) short bf16x8;
typedef __attribute__((ext_vector_type(4))) float f32x4;
typedef const __attribute__((address_space(1))) void gvoid_t;
typedef __attribute__((address_space(3))) void svoid_t;

static __device__ __forceinline__ unsigned short f2bf(float x) {
    unsigned u = __builtin_bit_cast(unsigned, x);
    return (unsigned short)((u + 0x7FFFu + ((u >> 16) & 1u)) >> 16);   // RNE
}
static __device__ __forceinline__ ushort4 f2bf4(float4 v) {
    ushort4 r; r.x = f2bf(v.x); r.y = f2bf(v.y); r.z = f2bf(v.z); r.w = f2bf(v.w); return r;
}
static __device__ __forceinline__ bf16x8 cvt8(float4 a, float4 b) {
    bf16x8 h;
    h[0] = (short)f2bf(a.x); h[1] = (short)f2bf(a.y); h[2] = (short)f2bf(a.z); h[3] = (short)f2bf(a.w);
    h[4] = (short)f2bf(b.x); h[5] = (short)f2bf(b.y); h[6] = (short)f2bf(b.z); h[7] = (short)f2bf(b.w);
    return h;
}

// ---------------- Kernel 1: QKV GEMM, plain bf16 MFMA ----------------
__global__ __launch_bounds__(256, 4) void k_qkv(const float* __restrict__ X,
                                                const float* __restrict__ Wp,
                                                unsigned short* __restrict__ qkvb) {
    __shared__ unsigned short Ah[128][72];
    __shared__ unsigned short Bh[128][72];
    const int t  = threadIdx.x;
    const int wv = t >> 6, ln = t & 63;
    const int lr = ln & 15;
    const int kq = (ln >> 4) * 8;
    const int rbase = (ln >> 4) * 4;
    const int m0 = (blockIdx.x / 18) * 128;
    const int j0 = (blockIdx.x % 18) * 128;
    const f32x4 zero4 = {0.f, 0.f, 0.f, 0.f};

    f32x4 acc[2][8];
#pragma unroll
    for (int rt = 0; rt < 2; ++rt)
#pragma unroll
        for (int ct = 0; ct < 8; ++ct) acc[rt][ct] = zero4;

    for (int k0 = 0; k0 < 768; k0 += 64) {
#pragma unroll
        for (int i = 0; i < 8; ++i) {
            const int q   = t + 256 * i;
            const int row = q >> 4;
            const int kc  = (q & 15) * 4;
            float4 xa = *reinterpret_cast<const float4*>(&X[(size_t)(m0 + row) * 768 + k0 + kc]);
            *reinterpret_cast<ushort4*>(&Ah[row][kc]) = f2bf4(xa);
            float4 wb = *reinterpret_cast<const float4*>(&Wp[(size_t)(j0 + row) * 768 + k0 + kc]);
            *reinterpret_cast<ushort4*>(&Bh[row][kc]) = f2bf4(wb);
        }
        __syncthreads();
#pragma unroll
        for (int ks = 0; ks < 2; ++ks) {
            const int kb = ks * 32 + kq;
            bf16x8 a0 = *reinterpret_cast<const bf16x8*>(&Ah[wv * 32 + lr][kb]);
            bf16x8 a1 = *reinterpret_cast<const bf16x8*>(&Ah[wv * 32 + 16 + lr][kb]);
#pragma unroll
            for (int ct = 0; ct < 8; ++ct) {
                bf16x8 bh = *reinterpret_cast<const bf16x8*>(&Bh[ct * 16 + lr][kb]);
                acc[0][ct] = __builtin_amdgcn_mfma_f32_16x16x32_bf16(a0, bh, acc[0][ct], 0, 0, 0);
                acc[1][ct] = __builtin_amdgcn_mfma_f32_16x16x32_bf16(a1, bh, acc[1][ct], 0, 0, 0);
            }
        }
        __syncthreads();
    }
#pragma unroll
    for (int rt = 0; rt < 2; ++rt)
#pragma unroll
        for (int ct = 0; ct < 8; ++ct)
#pragma unroll
            for (int r = 0; r < 4; ++r) {
                const int m = m0 + wv * 32 + rt * 16 + rbase + r;
                const int j = j0 + ct * 16 + lr;
                const int b = m >> 6, s = m & 63;
                const int n = j / 192, f = j % 192;
                qkvb[(((size_t)b * 12 + n) * 64 + s) * 192 + f] = f2bf(acc[rt][ct][r]);
            }
}

// ---------------- Kernel 2: attention per (b,n), plain bf16 MFMA ----------------
__global__ __launch_bounds__(256, 4) void k_attn(const unsigned short* __restrict__ qkvb,
                                                 float* __restrict__ msk,
                                                 unsigned short* __restrict__ Zh) {
    __shared__ unsigned short Qh[64][72];
    __shared__ unsigned short Kh[64][72];
    __shared__ unsigned short Vth[64][72];   // V transposed [d][s]
    __shared__ unsigned short Ph[64][72];
    const int t  = threadIdx.x;
    const int wv = t >> 6, ln = t & 63;
    const int lr = ln & 15;
    const int kq = (ln >> 4) * 8;
    const int rbase = (ln >> 4) * 4;
    const int bn = blockIdx.x;
    const int bb = bn / 12, nn = bn % 12;
    const unsigned short* base = qkvb + (size_t)bn * 12288;
    const f32x4 zero4 = {0.f, 0.f, 0.f, 0.f};

#pragma unroll
    for (int i = 0; i < 6; ++i) {
        const int q   = t + 256 * i;       // 1536 ushort8 granules
        const int row = q / 24;
        const int c8  = (q % 24) * 8;
        const int sec = c8 >> 6;
        const int d0  = c8 & 63;
        bf16x8 v = *reinterpret_cast<const bf16x8*>(&base[(size_t)row * 192 + c8]);
        if (sec == 0) {
            *reinterpret_cast<bf16x8*>(&Qh[row][d0]) = v;
        } else if (sec == 1) {
            *reinterpret_cast<bf16x8*>(&Kh[row][d0]) = v;
        } else {
#pragma unroll
            for (int jj = 0; jj < 8; ++jj) Vth[d0 + jj][row] = (unsigned short)v[jj];
        }
    }
    __syncthreads();

    f32x4 acc[4];
#pragma unroll
    for (int ct = 0; ct < 4; ++ct) acc[ct] = zero4;
#pragma unroll
    for (int ks = 0; ks < 2; ++ks) {
        const int kb = ks * 32 + kq;
        bf16x8 qh = *reinterpret_cast<const bf16x8*>(&Qh[wv * 16 + lr][kb]);
#pragma unroll
        for (int ct = 0; ct < 4; ++ct) {
            bf16x8 kh = *reinterpret_cast<const bf16x8*>(&Kh[ct * 16 + lr][kb]);
            acc[ct] = __builtin_amdgcn_mfma_f32_16x16x32_bf16(qh, kh, acc[ct], 0, 0, 0);
        }
    }

    float s_[4][4];
#pragma unroll
    for (int ct = 0; ct < 4; ++ct)
#pragma unroll
        for (int r = 0; r < 4; ++r) {
            const int row = wv * 16 + rbase + r;
            const int col = ct * 16 + lr;
            float s = (col > row) ? NEG_BIG : acc[ct][r] * 0.125f;
            s_[ct][r] = s;
            msk[(size_t)bn * 4096 + (size_t)row * 64 + col] = s;
        }
    float m[4], sum[4], p[4][4];
#pragma unroll
    for (int r = 0; r < 4; ++r)
        m[r] = fmaxf(fmaxf(s_[0][r], s_[1][r]), fmaxf(s_[2][r], s_[3][r]));
#pragma unroll
    for (int off = 1; off <= 8; off <<= 1)
#pragma unroll
        for (int r = 0; r < 4; ++r) m[r] = fmaxf(m[r], __shfl_xor(m[r], off));
#pragma unroll
    for (int r = 0; r < 4; ++r) sum[r] = 0.f;
#pragma unroll
    for (int ct = 0; ct < 4; ++ct)
#pragma unroll
        for (int r = 0; r < 4; ++r) { p[ct][r] = expf(s_[ct][r] - m[r]); sum[r] += p[ct][r]; }
#pragma unroll
    for (int off = 1; off <= 8; off <<= 1)
#pragma unroll
        for (int r = 0; r < 4; ++r) sum[r] += __shfl_xor(sum[r], off);
#pragma unroll
    for (int ct = 0; ct < 4; ++ct)
#pragma unroll
        for (int r = 0; r < 4; ++r)
            Ph[wv * 16 + rbase + r][ct * 16 + lr] = f2bf(p[ct][r] * (1.f / sum[r]));
    // wave-local LDS dependency only

    f32x4 o_[4];
#pragma unroll
    for (int ct = 0; ct < 4; ++ct) o_[ct] = zero4;
#pragma unroll
    for (int ks = 0; ks < 2; ++ks) {
        const int kb = ks * 32 + kq;
        bf16x8 ph = *reinterpret_cast<const bf16x8*>(&Ph[wv * 16 + lr][kb]);
#pragma unroll
        for (int ct = 0; ct < 4; ++ct) {
            bf16x8 vh = *reinterpret_cast<const bf16x8*>(&Vth[ct * 16 + lr][kb]);
            o_[ct] = __builtin_amdgcn_mfma_f32_16x16x32_bf16(ph, vh, o_[ct], 0, 0, 0);
        }
    }
    const int rt_z = bb >> 4;
#pragma unroll
    for (int ct = 0; ct < 4; ++ct)
#pragma unroll
        for (int r = 0; r < 4; ++r) {
            const int srow = wv * 16 + rbase + r;
            const int d    = ct * 16 + lr;
            const int k    = nn * 4096 + srow * 64 + d;
            const int lz   = (((k >> 3) & 3) << 4) + (bb & 15);
            const size_t zi = (((size_t)rt_z * 1536 + (k >> 5)) * 64 + lz) * 8 + (k & 7);
            Zh[zi] = f2bf(o_[ct][r]);
        }
}

// ---------------- Kernel 3: output projection v5 (LDS-shared Z) ----------------
// part[ksp][b][o] = sum_k Z[b][k] W[o][k]; 512 blocks = 16 ksp x 32 o-pairs.
// Both 64-col units computed in ONE K-loop sharing one Z stage.
// Z: triple-buffered LDS (3x8KB), 1 barrier/step. W: single 32KB wave-private
// swizzled buffer (lgkm guard before re-stage). vmcnt(2) steady state.
__global__ __launch_bounds__(256, 2) void k_lin(const unsigned short* __restrict__ Zh,
                                                const float* __restrict__ Wl,
                                                float* __restrict__ part) {
    __shared__ __align__(16) unsigned short Zs[3][8][64][8];   // 24 KB: [buf][rt*2+kf][lane][8]
    __shared__ __align__(16) float Ws[2][4][16][64];           // 32 KB: [unit][wave][row][64]
    const int t  = threadIdx.x;
    const int wv = t >> 6, ln = t & 63;
    const int lr = ln & 15;
    const int rbase = (ln >> 4) * 4;
    const int ksp = blockIdx.x >> 5;          // 0..15
    const int o0  = (blockIdx.x & 31) * 128;
    const int kf_base = ksp * 96;
    const int k_base  = ksp * 3072;
    const f32x4 zero4 = {0.f, 0.f, 0.f, 0.f};

    f32x4 acc[2][4];
#pragma unroll
    for (int u = 0; u < 2; ++u)
#pragma unroll
        for (int rt = 0; rt < 4; ++rt) acc[u][rt] = zero4;

#define ZSTAGE(buf_, ts_)                                                          \
    {                                                                              \
        _Pragma("unroll")                                                          \
        for (int q = 0; q < 2; ++q) {                                              \
            const int s_ = q * 4 + wv;                                             \
            const int rt_ = s_ >> 1, kfo = s_ & 1;                                 \
            const unsigned short* src = Zh +                                       \
                ((size_t)(rt_ * 1536 + kf_base + (ts_) * 2 + kfo) * 64 + ln) * 8;  \
            __builtin_amdgcn_global_load_lds((gvoid_t*)src,                        \
                (svoid_t*)&Zs[buf_][s_][0][0], 16, 0, 0);                          \
        }                                                                          \
    }

#define WSTAGE(ts_)                                                                \
    {                                                                              \
        const int k0 = k_base + (ts_) * 64;                                        \
        _Pragma("unroll")                                                          \
        for (int u = 0; u < 2; ++u)                                                \
            _Pragma("unroll")                                                      \
            for (int i = 0; i < 4; ++i) {                                          \
                const int row_l = i * 4 + (ln >> 4);                               \
                const int u_g   = (ln & 15) ^ (row_l & 7);                         \
                const float* src = Wl +                                            \
                    (size_t)(o0 + u * 64 + wv * 16 + row_l) * 49152 + k0 + u_g * 4;\
                __builtin_amdgcn_global_load_lds((gvoid_t*)src,                    \
                    (svoid_t*)&Ws[u][wv][i * 4][0], 16, 0, 0);                     \
            }                                                                      \
    }

    ZSTAGE(0, 0)
    WSTAGE(0)
    for (int ts = 0; ts < 48; ++ts) {
        if (ts + 1 < 48) {
            ZSTAGE((ts + 1) % 3, ts + 1)
            asm volatile("s_waitcnt vmcnt(2)" ::: "memory");   // Z(ts)+W(ts) done; Z(ts+1) in flight
        } else {
            asm volatile("s_waitcnt vmcnt(0)" ::: "memory");
        }
        __syncthreads();                                        // all waves' Z slots visible
        const int zb = ts % 3;
#pragma unroll
        for (int ks = 0; ks < 2; ++ks) {
            const int u0 = ks * 8 + (ln >> 4) * 2;
            bf16x8 wh[2];
#pragma unroll
            for (int u = 0; u < 2; ++u) {
                const char* rowp = (const char*)&Ws[u][wv][lr][0];
                float4 f0 = *reinterpret_cast<const float4*>(rowp + ((u0 ^ (lr & 7)) << 4));
                float4 f1 = *reinterpret_cast<const float4*>(rowp + (((u0 + 1) ^ (lr & 7)) << 4));
                wh[u] = cvt8(f0, f1);
            }
#pragma unroll
            for (int rt = 0; rt < 4; ++rt) {
                bf16x8 ah = *reinterpret_cast<const bf16x8*>(&Zs[zb][rt * 2 + ks][ln][0]);
                acc[0][rt] = __builtin_amdgcn_mfma_f32_16x16x32_bf16(ah, wh[0], acc[0][rt], 0, 0, 0);
                acc[1][rt] = __builtin_amdgcn_mfma_f32_16x16x32_bf16(ah, wh[1], acc[1][rt], 0, 0, 0);
            }
        }
        if (ts + 1 < 48) {
            // guard: all my ds_reads of Ws complete before gload_lds overwrites it
            asm volatile("s_waitcnt lgkmcnt(0)" ::: "memory");
            __builtin_amdgcn_sched_barrier(0);
            WSTAGE(ts + 1)
        }
    }
#undef ZSTAGE
#undef WSTAGE

#pragma unroll
    for (int u = 0; u < 2; ++u) {
        const int ocol = o0 + u * 64 + wv * 16 + lr;
#pragma unroll
        for (int rt = 0; rt < 4; ++rt)
#pragma unroll
            for (int r = 0; r < 4; ++r)
                part[((size_t)ksp * 64 + rt * 16 + rbase + r) * 4096 + ocol] = acc[u][rt][r];
    }
}

// ---------------- Kernel 4: reduce 16 split-K partials + bias ----------------
__global__ __launch_bounds__(256) void k_reduce(const float* __restrict__ part,
                                                const float* __restrict__ bias,
                                                float* __restrict__ y) {
    const int idx = blockIdx.x * 256 + threadIdx.x;
    const int o = idx & 4095;
    const int b = idx >> 12;
    float s = bias[o];
#pragma unroll
    for (int ksp = 0; ksp < 16; ++ksp)
        s += part[((size_t)ksp * 64 + b) * 4096 + o];
    y[idx] = s;
}

extern "C" void kernel_launch(void* const* d_in, const int* in_sizes, int n_in,
                              void* d_out, int out_size, void* d_ws, size_t ws_size,
                              hipStream_t stream) {
    const float* x  = (const float*)d_in[0];
    const float* Wp = (const float*)d_in[1];
    const float* Wl = (const float*)d_in[2];
    const float* bl = (const float*)d_in[3];
    float* out = (float*)d_out;

    unsigned short* qkvb = (unsigned short*)d_ws;                       // 9437184 u16
    unsigned short* Zh   = (unsigned short*)((char*)d_ws + 18874368);   // 3145728 u16
    float*          part = (float*)((char*)d_ws + 25165824);            // 16x64x4096 f32
    float* y    = out;
    float* msk  = out + 262144;

    hipLaunchKernelGGL(k_qkv,    dim3(576),  dim3(256), 0, stream, x, Wp, qkvb);
    hipLaunchKernelGGL(k_attn,   dim3(768),  dim3(256), 0, stream, qkvb, msk, Zh);
    hipLaunchKernelGGL(k_lin,    dim3(512),  dim3(256), 0, stream, Zh, Wl, part);
    hipLaunchKernelGGL(k_reduce, dim3(1024), dim3(256), 0, stream, part, bl, y);
}